// Round 11
// baseline (235.695 us; speedup 1.0000x reference)
//
#include <hip/hip_runtime.h>

// H2G2: 2-layer RGCN (R=4, per-relation mean) + mean-pool + linear.
// R1->R2: atomic scatter -> CSR gather. R2->R3: atomic pool -> segmented pool+cls.
// R3->R4: fp32 LDS GEMM -> bf16 MFMA. R4->R5: CSR via 2-level bucket sort.
// R5->R7: aggregate-then-transform; K=320 MFMA. R8 FAILED (LDS-Y occupancy cap).
// R9: 8-deep gather agg. R10: register-resident Y fusion (lane owns its A-frag
//   channels), 227us; layer latency-bound (occ 23%, VALU 15%).
// R11: merge the 4 per-relation gather loops into ONE loop over the node's
//   edge list (divergence: 4 short maxes -> 1 long max), relation selected
//   per edge via masked-FMA weights w_r in {0, inv_r} (scale folded in);
//   4-edge unroll = 8 row-loads in flight. rp4 dropped.

#define RR 4
#define HH 64
#define KK 320         // (RR+1)*HH
#define LWN (HH * KK)  // weights per layer = 20480
#define EPB 4096       // edges per binning block
#define SBUF_D 6144    // per-bucket staging cap

using frag_ab = __attribute__((ext_vector_type(8))) short;
using frag_cd = __attribute__((ext_vector_type(4))) float;

__device__ inline short f2bf(float f) {
    unsigned u = __builtin_bit_cast(unsigned, f);
    unsigned r = u + 0x7fffu + ((u >> 16) & 1u);  // RNE
    return (short)(r >> 16);
}
__device__ inline float bf2f(short s) {
    unsigned u = ((unsigned)(unsigned short)s) << 16;
    return __builtin_bit_cast(float, u);
}

// ---- prep: fused init-independent work, partitioned by blockIdx ----
__global__ __launch_bounds__(256) void prep_kernel(
    const int* __restrict__ dst, int E, int NBUCK, int* __restrict__ bcnt,
    const float* __restrict__ basis1, const float* __restrict__ comp1, const float* __restrict__ root1,
    const float* __restrict__ basis2, const float* __restrict__ comp2, const float* __restrict__ root2,
    short* __restrict__ W1t, short* __restrict__ W2t,
    const int* __restrict__ batch, int* __restrict__ gstart, int N, int G,
    int* __restrict__ row_ptr,
    const float* __restrict__ x, short* __restrict__ Xb,
    int ebl, int wbl, int nb) {
    const int bid = blockIdx.x;
    const int t = threadIdx.x;
    if (bid < ebl) {  // ---- histogram of dst>>8 ----
        __shared__ int lc[256];
        lc[t] = 0;
        __syncthreads();
        int e0 = bid * EPB, e1 = min(e0 + EPB, E);
        for (int e = e0 + t; e < e1; e += 256) atomicAdd(&lc[dst[e] >> 8], 1);
        __syncthreads();
        if (t < NBUCK && lc[t]) atomicAdd(&bcnt[t], lc[t]);
    } else if (bid < ebl + wbl) {  // ---- weights: Wt[c*320+k] = Wstack[k][c] ----
        int w = (bid - ebl) * 256 + t;
        int layer = w / LWN;
        int rem = w - layer * LWN;
        int c = rem / KK;
        int k = rem - c * KK;
        const float* basis = layer ? basis2 : basis1;
        const float* comp  = layer ? comp2  : comp1;
        const float* root  = layer ? root2  : root1;
        short* Wt          = layer ? W2t    : W1t;
        float v;
        if (k < HH) {
            v = root[k * HH + c];
        } else {
            int r = (k >> 6) - 1, kk = k & 63;
            v = 0.f;
#pragma unroll
            for (int b = 0; b < RR; ++b) v += comp[r * RR + b] * basis[(b * HH + kk) * HH + c];
        }
        Wt[c * KK + k] = f2bf(v);
    } else if (bid < ebl + wbl + nb) {  // ---- gstart + row_ptr sentinel ----
        int i = (bid - ebl - wbl) * 256 + t;
        if (i == 0) row_ptr[N] = E;
        if (i < N) {
            int b1 = batch[i];
            int b0 = (i == 0) ? -1 : batch[i - 1];
            for (int g = b0 + 1; g <= b1; ++g) gstart[g] = i;
            if (i == N - 1)
                for (int g = b1 + 1; g <= G; ++g) gstart[g] = N;
        }
    } else {  // ---- convert x fp32 -> bf16 ----
        int i4 = (bid - ebl - wbl - nb) * 256 + t;
        int base = i4 * 4;
        if (base < N * 64) {
            float4 f = *(const float4*)&x[base];
            short4 s;
            s.x = f2bf(f.x); s.y = f2bf(f.y); s.z = f2bf(f.z); s.w = f2bf(f.w);
            *(short4*)&Xb[base] = s;
        }
    }
}

// ---- bin: block-local counting sort by bucket; packed payload src:16|et:2|dl:8 ----
__global__ __launch_bounds__(256) void bin_kernel(const int* __restrict__ src,
                                                  const int* __restrict__ dst,
                                                  const int* __restrict__ et,
                                                  const int* __restrict__ bcnt,
                                                  int* __restrict__ cur0,
                                                  int* __restrict__ tmp, int E) {
    __shared__ int lc[256];
    __shared__ int lscan[257];
    __shared__ int lbase[256];
    __shared__ int ss[256];
    __shared__ int sbuf[EPB];
    int t = threadIdx.x;
    int bv = bcnt[t];
    ss[t] = bv;
    __syncthreads();
#pragma unroll
    for (int off = 1; off < 256; off <<= 1) {
        int u = (t >= off) ? ss[t - off] : 0;
        __syncthreads();
        ss[t] += u;
        __syncthreads();
    }
    int boff_t = ss[t] - bv;
    lc[t] = 0;
    __syncthreads();
    int e0 = blockIdx.x * EPB;
    int e1 = min(e0 + EPB, E);
    for (int e = e0 + t; e < e1; e += 256) atomicAdd(&lc[dst[e] >> 8], 1);
    __syncthreads();
    int v = lc[t];
    ss[t] = v;
    __syncthreads();
#pragma unroll
    for (int off = 1; off < 256; off <<= 1) {
        int u = (t >= off) ? ss[t - off] : 0;
        __syncthreads();
        ss[t] += u;
        __syncthreads();
    }
    lscan[t] = ss[t] - v;
    if (t == 255) lscan[256] = ss[255];
    if (v) lbase[t] = boff_t + atomicAdd(&cur0[t], v);
    lc[t] = 0;
    __syncthreads();
    for (int e = e0 + t; e < e1; e += 256) {
        int d = dst[e];
        int b = d >> 8;
        int p = (src[e] << 10) | (et[e] << 8) | (d & 255);
        int pos = lscan[b] + atomicAdd(&lc[b], 1);
        sbuf[pos] = p;
    }
    __syncthreads();
    int tot = lscan[256];
    for (int i = t; i < tot; i += 256) {
        int lo = 0, hi = 255;
        while (lo < hi) { int mid = (lo + hi + 1) >> 1; if (lscan[mid] <= i) lo = mid; else hi = mid - 1; }
        tmp[lbase[lo] + (i - lscan[lo])] = sbuf[i];
    }
}

// ---- csr: per-bucket finalize: row_ptr, inv, eidx sorted by (dst, rel) ----
__global__ __launch_bounds__(256) void csr_kernel(const int* __restrict__ tmp,
                                                  const int* __restrict__ bcnt,
                                                  int* __restrict__ row_ptr,
                                                  int* __restrict__ eidx,
                                                  float* __restrict__ inv, int N) {
    __shared__ int cnt4l[1024];  // counts -> in-place per-(dl,r) start offsets/cursors
    __shared__ int dscan[256];
    __shared__ int ss[256];
    __shared__ int sb[SBUF_D];
    int b = blockIdx.x, t = threadIdx.x;
    int bv = bcnt[t];
    ss[t] = bv;
    __syncthreads();
#pragma unroll
    for (int off = 1; off < 256; off <<= 1) {
        int u = (t >= off) ? ss[t - off] : 0;
        __syncthreads();
        ss[t] += u;
        __syncthreads();
    }
    __shared__ int s0s, s1s;
    if (t == b) { s0s = ss[t] - bv; s1s = ss[t]; }
    __syncthreads();
    int s0 = s0s, s1 = s1s;
    int len = s1 - s0;
    for (int i = t; i < 1024; i += 256) cnt4l[i] = 0;
    __syncthreads();
    for (int i = s0 + t; i < s1; i += 256) {
        int e = tmp[i];
        atomicAdd(&cnt4l[((e & 255) << 2) | ((e >> 8) & 3)], 1);
    }
    __syncthreads();
    int c0 = cnt4l[t * 4], c1 = cnt4l[t * 4 + 1], c2 = cnt4l[t * 4 + 2], c3 = cnt4l[t * 4 + 3];
    int deg = c0 + c1 + c2 + c3;
    ss[t] = deg;
    __syncthreads();
#pragma unroll
    for (int off = 1; off < 256; off <<= 1) {
        int u = (t >= off) ? ss[t - off] : 0;
        __syncthreads();
        ss[t] += u;
        __syncthreads();
    }
    dscan[t] = ss[t] - deg;
    int d0 = b << 8;
    int d = d0 + t;
    if (d < N) {
        inv[d * 4 + 0] = 1.0f / fmaxf((float)c0, 1.0f);
        inv[d * 4 + 1] = 1.0f / fmaxf((float)c1, 1.0f);
        inv[d * 4 + 2] = 1.0f / fmaxf((float)c2, 1.0f);
        inv[d * 4 + 3] = 1.0f / fmaxf((float)c3, 1.0f);
    }
    int base = dscan[t];
    cnt4l[t * 4] = base;
    cnt4l[t * 4 + 1] = base + c0;
    cnt4l[t * 4 + 2] = base + c0 + c1;
    cnt4l[t * 4 + 3] = base + c0 + c1 + c2;
    if (d < N) row_ptr[d] = s0 + base;
    __syncthreads();
    if (len <= SBUF_D) {
        for (int i = s0 + t; i < s1; i += 256) {
            int e = tmp[i];
            int key = ((e & 255) << 2) | ((e >> 8) & 3);
            int pos = atomicAdd(&cnt4l[key], 1);
            sb[pos] = ((e >> 10) << 2) | ((e >> 8) & 3);  // (src<<2)|et
        }
        __syncthreads();
        for (int i = t; i < len; i += 256) eidx[s0 + i] = sb[i];
    } else {
        for (int i = s0 + t; i < s1; i += 256) {
            int e = tmp[i];
            int key = ((e & 255) << 2) | ((e >> 8) & 3);
            int pos = atomicAdd(&cnt4l[key], 1);
            eidx[s0 + pos] = ((e >> 10) << 2) | ((e >> 8) & 3);
        }
    }
}

// ---- fused layer: register-resident Y; single merged gather loop, masked-FMA
// relation select (w_r in {0, inv_r}); 4-edge unroll = 8 loads in flight ----
__global__ __launch_bounds__(256) void layer_kernel(const int* __restrict__ row_ptr,
                                                    const int* __restrict__ eidx,
                                                    const short* __restrict__ Xb,
                                                    const float* __restrict__ inv,
                                                    const short* __restrict__ Wt,
                                                    const float* __restrict__ bias,
                                                    short* __restrict__ out, int n) {
    const int t = threadIdx.x;
    const int wv = t >> 6;
    const int l = t & 63;
    const int m = l & 15;
    const int quad = l >> 4;
    const int node = blockIdx.x * 64 + wv * 16 + m;
    const bool valid = node < n;

    float accL[4][8], accH[4][8];
#pragma unroll
    for (int r = 0; r < 4; ++r)
#pragma unroll
        for (int j = 0; j < 8; ++j) { accL[r][j] = 0.f; accH[r][j] = 0.f; }

    int k0 = 0, k1 = 0;
    float4 iv = make_float4(0.f, 0.f, 0.f, 0.f);
    if (valid) {
        k0 = row_ptr[node];
        k1 = row_ptr[node + 1];
        iv = *(const float4*)&inv[node * 4];
    }
    const short* xbq = Xb + quad * 8;

#define EDGE(P, XL, XH)                                                       \
    {                                                                         \
        int r = (P) & 3;                                                      \
        float w0 = (r == 0) ? iv.x : 0.f;                                     \
        float w1 = (r == 1) ? iv.y : 0.f;                                     \
        float w2 = (r == 2) ? iv.z : 0.f;                                     \
        float w3 = (r == 3) ? iv.w : 0.f;                                     \
        _Pragma("unroll") for (int j = 0; j < 8; ++j) {                       \
            float vl = bf2f((XL)[j]);                                         \
            float vh = bf2f((XH)[j]);                                         \
            accL[0][j] += vl * w0; accH[0][j] += vh * w0;                     \
            accL[1][j] += vl * w1; accH[1][j] += vh * w1;                     \
            accL[2][j] += vl * w2; accH[2][j] += vh * w2;                     \
            accL[3][j] += vl * w3; accH[3][j] += vh * w3;                     \
        }                                                                     \
    }

    int k = k0;
    for (; k + 3 < k1; k += 4) {
        int p0 = eidx[k], p1 = eidx[k + 1], p2 = eidx[k + 2], p3 = eidx[k + 3];
        const short* q0 = xbq + (size_t)(p0 >> 2) * 64;
        const short* q1 = xbq + (size_t)(p1 >> 2) * 64;
        const short* q2 = xbq + (size_t)(p2 >> 2) * 64;
        const short* q3 = xbq + (size_t)(p3 >> 2) * 64;
        frag_ab x0l = *(const frag_ab*)q0, x0h = *(const frag_ab*)(q0 + 32);
        frag_ab x1l = *(const frag_ab*)q1, x1h = *(const frag_ab*)(q1 + 32);
        frag_ab x2l = *(const frag_ab*)q2, x2h = *(const frag_ab*)(q2 + 32);
        frag_ab x3l = *(const frag_ab*)q3, x3h = *(const frag_ab*)(q3 + 32);
        EDGE(p0, x0l, x0h)
        EDGE(p1, x1l, x1h)
        EDGE(p2, x2l, x2h)
        EDGE(p3, x3l, x3h)
    }
    for (; k < k1; ++k) {
        int p0 = eidx[k];
        const short* q0 = xbq + (size_t)(p0 >> 2) * 64;
        frag_ab x0l = *(const frag_ab*)q0, x0h = *(const frag_ab*)(q0 + 32);
        EDGE(p0, x0l, x0h)
    }
#undef EDGE

    // build A-frags: a[0..1] = X row; a[2+2r], a[3+2r] = Y_r (already scaled)
    frag_ab a[10];
#pragma unroll
    for (int f = 0; f < 10; ++f) a[f] = frag_ab{};
    if (valid) {
        const short* xr = Xb + (size_t)node * 64 + quad * 8;
        a[0] = *(const frag_ab*)xr;
        a[1] = *(const frag_ab*)(xr + 32);
    }
#pragma unroll
    for (int r = 0; r < 4; ++r)
#pragma unroll
        for (int j = 0; j < 8; ++j) {
            a[2 + 2 * r][j] = f2bf(accL[r][j]);
            a[3 + 2 * r][j] = f2bf(accH[r][j]);
        }

    const int nrow_base = blockIdx.x * 64 + wv * 16 + quad * 4;
#pragma unroll
    for (int ct = 0; ct < 4; ++ct) {
        const short* bp = Wt + (size_t)(ct * 16 + m) * KK + quad * 8;
        frag_cd acc = {0.f, 0.f, 0.f, 0.f};
#pragma unroll
        for (int f = 0; f < 10; ++f) {
            frag_ab bf = *(const frag_ab*)(bp + f * 32);
            acc = __builtin_amdgcn_mfma_f32_16x16x32_bf16(a[f], bf, acc, 0, 0, 0);
        }
        int col = ct * 16 + m;
        float bv = bias[col];
#pragma unroll
        for (int r = 0; r < 4; ++r) {
            int nr = nrow_base + r;
            if (nr < n) out[(size_t)nr * 64 + col] = f2bf(fmaxf(acc[r] + bv, 0.f));
        }
    }
}

// ---- pool (segmented) + classifier ----
__global__ __launch_bounds__(256) void pool_cls_kernel(const short* __restrict__ h2,
                                                       const int* __restrict__ gstart,
                                                       const float* __restrict__ w,
                                                       const float* __restrict__ b,
                                                       float* __restrict__ out) {
    __shared__ float red[4][64];
    const int g = blockIdx.x;
    const int t = threadIdx.x;
    const int h = t & 63;
    const int wv = t >> 6;
    const int s = gstart[g], e = gstart[g + 1];

    float acc = 0.f;
    for (int i = s + wv; i < e; i += 4) acc += bf2f(h2[(size_t)i * 64 + h]);
    red[wv][h] = acc;
    __syncthreads();
    if (wv == 0) {
        float sum = red[0][h] + red[1][h] + red[2][h] + red[3][h];
        red[0][h] = sum / fmaxf((float)(e - s), 1.0f);
    }
    __syncthreads();
    if (t < 4) {
        float sres = 0.f;
#pragma unroll 8
        for (int hh = 0; hh < 64; ++hh) sres += red[0][hh] * w[hh * 4 + t];
        out[g * 4 + t] = sres + b[t];
    }
}

extern "C" void kernel_launch(void* const* d_in, const int* in_sizes, int n_in,
                              void* d_out, int out_size, void* d_ws, size_t ws_size,
                              hipStream_t stream) {
    const float* x        = (const float*)d_in[0];
    const int* edge_index = (const int*)d_in[1];
    const int* edge_type  = (const int*)d_in[2];
    const int* batch      = (const int*)d_in[3];
    const float* basis1 = (const float*)d_in[4];
    const float* comp1  = (const float*)d_in[5];
    const float* root1  = (const float*)d_in[6];
    const float* bias1  = (const float*)d_in[7];
    const float* basis2 = (const float*)d_in[8];
    const float* comp2  = (const float*)d_in[9];
    const float* root2  = (const float*)d_in[10];
    const float* bias2  = (const float*)d_in[11];
    const float* clas_w = (const float*)d_in[12];
    const float* clas_b = (const float*)d_in[13];

    const int N = in_sizes[0] / 64;
    const int E = in_sizes[2];
    const int G = out_size / 4;
    const int* src = edge_index;
    const int* dst = edge_index + E;
    const int NBUCK = (N + 255) >> 8;

    char* base = (char*)d_ws;
    size_t off = 0;
    auto carve = [&](size_t bytes) { void* p = base + off; off = (off + bytes + 15) & ~(size_t)15; return p; };
    int*   bcnt    = (int*)carve(sizeof(int) * 256);
    int*   cur0    = (int*)carve(sizeof(int) * 256);
    int*   row_ptr = (int*)carve(sizeof(int) * ((size_t)N + 1));
    int*   gstart  = (int*)carve(sizeof(int) * ((size_t)G + 1));
    int*   eidx    = (int*)carve(sizeof(int) * (size_t)E);
    int*   tmp     = (int*)carve(sizeof(int) * (size_t)E);
    float* inv     = (float*)carve(sizeof(float) * (size_t)N * RR);
    short* W1t     = (short*)carve(sizeof(short) * LWN);
    short* W2t     = (short*)carve(sizeof(short) * LWN);
    short* Xb1     = (short*)carve(sizeof(short) * (size_t)N * 64);
    short* H1      = (short*)carve(sizeof(short) * (size_t)N * 64);
    short* H2      = (short*)carve(sizeof(short) * (size_t)N * 64);

    const int nb  = (N + 255) / 256;
    const int ebl = (E + EPB - 1) / EPB;
    const int wbl = (2 * LWN + 255) / 256;
    const int cvb = (N * 64 / 4 + 255) / 256;
    const int prep_blocks = ebl + wbl + nb + cvb;

    hipMemsetAsync(bcnt, 0, sizeof(int) * 512, stream);  // bcnt + cur0

    prep_kernel<<<prep_blocks, 256, 0, stream>>>(
        dst, E, NBUCK, bcnt,
        basis1, comp1, root1, basis2, comp2, root2, W1t, W2t,
        batch, gstart, N, G, row_ptr, x, Xb1, ebl, wbl, nb);
    bin_kernel<<<ebl, 256, 0, stream>>>(src, dst, edge_type, bcnt, cur0, tmp, E);
    csr_kernel<<<NBUCK, 256, 0, stream>>>(tmp, bcnt, row_ptr, eidx, inv, N);

    const int layer_blocks = (N + 63) / 64;

    layer_kernel<<<layer_blocks, 256, 0, stream>>>(row_ptr, eidx, Xb1, inv, W1t, bias1, H1, N);
    layer_kernel<<<layer_blocks, 256, 0, stream>>>(row_ptr, eidx, H1, inv, W2t, bias2, H2, N);

    pool_cls_kernel<<<G, 256, 0, stream>>>(H2, gstart, clas_w, clas_b, (float*)d_out);
}